// Round 3
// baseline (1794.508 us; speedup 1.0000x reference)
//
#include <hip/hip_runtime.h>
#include <math.h>

#define VOCAB 100000
#define DIM   128
#define BATCH 2048
#define HIST  50
#define TOPK  10
#define NCAND 32

#define VPAD  100096              // VOCAB rounded up to multiple of 128
#define NBLK  782                 // VPAD/128 column blocks
#define MBLK  16                  // 2048/128 row blocks
#define NWG   (NBLK*MBLK)         // 12512 blocks (divisible by 8 XCDs)
#define CPX   (NWG/8)             // 1564 blocks per XCD chunk

typedef __attribute__((ext_vector_type(8)))  short bf16x8;
typedef __attribute__((ext_vector_type(16))) float f32x16;

// ---------------------------------------------------------------------------
// fp32 -> 3x bf16 limb split (RNE at each step; h+m+l captures 24 mantissa
// bits, residual ~2^-24 relative => below fp32-reference accumulation noise).
// ---------------------------------------------------------------------------
__device__ __forceinline__ ushort bf16_rne(float x) {
    unsigned u = __float_as_uint(x);
    return (ushort)((u + 0x7FFFu + ((u >> 16) & 1u)) >> 16);
}
__device__ __forceinline__ float bf16_tof(ushort h) {
    return __uint_as_float(((unsigned)h) << 16);
}
__device__ __forceinline__ void split3(float x, ushort& h, ushort& m, ushort& l) {
    h = bf16_rne(x);
    float r1 = x - bf16_tof(h);
    m = bf16_rne(r1);
    float r2 = r1 - bf16_tof(m);
    l = bf16_rne(r2);
}

// ---------------------------------------------------------------------------
// Kernel P: convert label table L[100000,128] fp32 -> 3 bf16 limb arrays,
// zero-padded to VPAD rows so GEMM staging never reads OOB.
// ---------------------------------------------------------------------------
__global__ __launch_bounds__(256) void conv_kernel(
    const float* __restrict__ L,
    ushort* __restrict__ Lh, ushort* __restrict__ Lm, ushort* __restrict__ Ll)
{
    const int i4 = blockIdx.x * 256 + threadIdx.x;   // float4 index; grid covers VPAD*32
    const int v  = i4 >> 5;                          // row (32 float4 per 128-wide row)
    float4 f = make_float4(0.f, 0.f, 0.f, 0.f);
    if (v < VOCAB) f = ((const float4*)L)[i4];
    float s[4] = {f.x, f.y, f.z, f.w};
    ushort h[4], m[4], l[4];
    #pragma unroll
    for (int j = 0; j < 4; ++j) split3(s[j], h[j], m[j], l[j]);
    ((ushort4*)Lh)[i4] = make_ushort4(h[0], h[1], h[2], h[3]);
    ((ushort4*)Lm)[i4] = make_ushort4(m[0], m[1], m[2], m[3]);
    ((ushort4*)Ll)[i4] = make_ushort4(l[0], l[1], l[2], l[3]);
}

// ---------------------------------------------------------------------------
// Kernel A: context encoder in fp64, rounded to fp32; also emits bf16 limbs
// of ctx for the MFMA GEMM (when ch != nullptr).
// ---------------------------------------------------------------------------
__global__ __launch_bounds__(128) void ctx_kernel(
    const int* __restrict__ ids, const float* __restrict__ cet,
    const float* __restrict__ W, const float* __restrict__ bias,
    float* __restrict__ ctx32,
    ushort* __restrict__ ch, ushort* __restrict__ cm, ushort* __restrict__ cl)
{
    int b = blockIdx.x;
    int d = threadIdx.x;
    __shared__ int sids[HIST];
    __shared__ double pooled[DIM];
    if (d < HIST) sids[d] = ids[b * HIST + d];
    __syncthreads();
    double s = 0.0;
    for (int h = 0; h < HIST; ++h)
        s += (double)cet[(long)sids[h] * DIM + d];
    pooled[d] = s / (double)HIST;
    __syncthreads();
    double acc = (double)bias[d];
    #pragma unroll 4
    for (int k = 0; k < DIM; ++k)
        acc += pooled[k] * (double)W[k * DIM + d];
    float v = (float)acc;
    ctx32[b * DIM + d] = v;
    if (ch) {
        ushort hh, mm, ll;
        split3(v, hh, mm, ll);
        ch[b * DIM + d] = hh;
        cm[b * DIM + d] = mm;
        cl[b * DIM + d] = ll;
    }
}

// ---------------------------------------------------------------------------
// Kernel B: split-bf16 MFMA GEMM.
//   logits[2048,100000] = ctx @ L^T  via 6 limb products (hh,hm,mh,hl,lh,mm)
//   on v_mfma_f32_32x32x16_bf16, fp32 accumulation.
// 128x128 tile, 256 thr = 4 waves, wave -> 64x64 (2x2 frags of 32x32).
// B limbs staged in LDS (K split in two 64-steps, 48 KB, XOR-swizzled 16B
// slots); A limb fragments read straight from L2-resident ctx limb arrays.
// C/D layout (verified m74/m101): col = lane&31, row = (reg&3)+8*(reg>>2)+4*(lane>>5).
// ---------------------------------------------------------------------------
__global__ __launch_bounds__(256, 2) void mfma_gemm(
    const ushort* __restrict__ ch, const ushort* __restrict__ cm,
    const ushort* __restrict__ cl,
    const ushort* __restrict__ Lh, const ushort* __restrict__ Lm,
    const ushort* __restrict__ Ll,
    float* __restrict__ out)
{
    __shared__ ushort Bh[128 * 64];   // 16 KB each, rows of 64 ushort = 128 B
    __shared__ ushort Bm[128 * 64];
    __shared__ ushort Bl[128 * 64];

    const int bid = blockIdx.x;
    const int sw  = (bid & 7) * CPX + (bid >> 3);   // XCD-chunked swizzle (bijective)
    const int mb  = sw & 15, nb = sw >> 4;          // mb fastest: 16 blocks share a B panel
    const int bm0 = mb << 7, bn0 = nb << 7;

    const int t   = threadIdx.x;
    const int wid = t >> 6, l = t & 63;
    const int wr  = wid >> 1, wc = wid & 1;         // wave -> 64x64 subtile
    const int la  = l & 31, kh = l >> 5;

    f32x16 acc00 = {}, acc01 = {}, acc10 = {}, acc11 = {};

    const int a0 = (bm0 + wr * 64 + la) * DIM;      // A row base (mi=0), ushort units
    const int n0 = wc * 64 + la;                    // local B row (ni=0)
    const int n1 = n0 + 32;

    for (int ks = 0; ks < 2; ++ks) {
        const int k0 = ks * 64;                     // global k offset (ushort units)
        __syncthreads();                            // protect prior step's reads
        // --- stage B limbs: 1024 16B-chunks per array, 4 per thread ---
        #pragma unroll
        for (int i = 0; i < 4; ++i) {
            const int j    = t + 256 * i;           // chunk id
            const int row  = j >> 3;                // 8 chunks per 128B row-half
            const int c16  = j & 7;
            const int gidx = (nb * 128 + row) * DIM + k0 + c16 * 8;
            const int didx = row * 64 + ((c16 ^ (row & 7)) * 8);   // XOR swizzle
            *(bf16x8*)&Bh[didx] = *(const bf16x8*)&Lh[gidx];
            *(bf16x8*)&Bm[didx] = *(const bf16x8*)&Lm[gidx];
            *(bf16x8*)&Bl[didx] = *(const bf16x8*)&Ll[gidx];
        }
        __syncthreads();

        // --- MFMA: 4 k-chunks of 16, 2x2 frags, 6 limb products each ---
        #pragma unroll
        for (int kk = 0; kk < 4; ++kk) {
            const int kg = k0 + kk * 16 + kh * 8;
            bf16x8 ah0 = *(const bf16x8*)&ch[a0 + kg];
            bf16x8 am0 = *(const bf16x8*)&cm[a0 + kg];
            bf16x8 al0 = *(const bf16x8*)&cl[a0 + kg];
            bf16x8 ah1 = *(const bf16x8*)&ch[a0 + 32 * DIM + kg];
            bf16x8 am1 = *(const bf16x8*)&cm[a0 + 32 * DIM + kg];
            bf16x8 al1 = *(const bf16x8*)&cl[a0 + 32 * DIM + kg];

            const int c16 = kk * 2 + kh;
            const int d0  = n0 * 64 + ((c16 ^ (n0 & 7)) * 8);
            const int d1  = n1 * 64 + ((c16 ^ (n1 & 7)) * 8);
            bf16x8 bh0 = *(const bf16x8*)&Bh[d0];
            bf16x8 bm0v = *(const bf16x8*)&Bm[d0];
            bf16x8 bl0 = *(const bf16x8*)&Bl[d0];
            bf16x8 bh1 = *(const bf16x8*)&Bh[d1];
            bf16x8 bm1v = *(const bf16x8*)&Bm[d1];
            bf16x8 bl1 = *(const bf16x8*)&Bl[d1];

            // (mi=0,ni=0)
            acc00 = __builtin_amdgcn_mfma_f32_32x32x16_bf16(ah0, bh0,  acc00, 0, 0, 0);
            acc00 = __builtin_amdgcn_mfma_f32_32x32x16_bf16(ah0, bm0v, acc00, 0, 0, 0);
            acc00 = __builtin_amdgcn_mfma_f32_32x32x16_bf16(am0, bh0,  acc00, 0, 0, 0);
            acc00 = __builtin_amdgcn_mfma_f32_32x32x16_bf16(ah0, bl0,  acc00, 0, 0, 0);
            acc00 = __builtin_amdgcn_mfma_f32_32x32x16_bf16(al0, bh0,  acc00, 0, 0, 0);
            acc00 = __builtin_amdgcn_mfma_f32_32x32x16_bf16(am0, bm0v, acc00, 0, 0, 0);
            // (mi=0,ni=1)
            acc01 = __builtin_amdgcn_mfma_f32_32x32x16_bf16(ah0, bh1,  acc01, 0, 0, 0);
            acc01 = __builtin_amdgcn_mfma_f32_32x32x16_bf16(ah0, bm1v, acc01, 0, 0, 0);
            acc01 = __builtin_amdgcn_mfma_f32_32x32x16_bf16(am0, bh1,  acc01, 0, 0, 0);
            acc01 = __builtin_amdgcn_mfma_f32_32x32x16_bf16(ah0, bl1,  acc01, 0, 0, 0);
            acc01 = __builtin_amdgcn_mfma_f32_32x32x16_bf16(al0, bh1,  acc01, 0, 0, 0);
            acc01 = __builtin_amdgcn_mfma_f32_32x32x16_bf16(am0, bm1v, acc01, 0, 0, 0);
            // (mi=1,ni=0)
            acc10 = __builtin_amdgcn_mfma_f32_32x32x16_bf16(ah1, bh0,  acc10, 0, 0, 0);
            acc10 = __builtin_amdgcn_mfma_f32_32x32x16_bf16(ah1, bm0v, acc10, 0, 0, 0);
            acc10 = __builtin_amdgcn_mfma_f32_32x32x16_bf16(am1, bh0,  acc10, 0, 0, 0);
            acc10 = __builtin_amdgcn_mfma_f32_32x32x16_bf16(ah1, bl0,  acc10, 0, 0, 0);
            acc10 = __builtin_amdgcn_mfma_f32_32x32x16_bf16(al1, bh0,  acc10, 0, 0, 0);
            acc10 = __builtin_amdgcn_mfma_f32_32x32x16_bf16(am1, bm0v, acc10, 0, 0, 0);
            // (mi=1,ni=1)
            acc11 = __builtin_amdgcn_mfma_f32_32x32x16_bf16(ah1, bh1,  acc11, 0, 0, 0);
            acc11 = __builtin_amdgcn_mfma_f32_32x32x16_bf16(ah1, bm1v, acc11, 0, 0, 0);
            acc11 = __builtin_amdgcn_mfma_f32_32x32x16_bf16(am1, bh1,  acc11, 0, 0, 0);
            acc11 = __builtin_amdgcn_mfma_f32_32x32x16_bf16(ah1, bl1,  acc11, 0, 0, 0);
            acc11 = __builtin_amdgcn_mfma_f32_32x32x16_bf16(al1, bh1,  acc11, 0, 0, 0);
            acc11 = __builtin_amdgcn_mfma_f32_32x32x16_bf16(am1, bm1v, acc11, 0, 0, 0);
        }
    }

    // --- epilogue: C/D col = la, row = (r&3)+8*(r>>2)+4*kh ---
    const int rb = bm0 + wr * 64 + kh * 4;
    #pragma unroll
    for (int mi = 0; mi < 2; ++mi) {
        #pragma unroll
        for (int ni = 0; ni < 2; ++ni) {
            const int col = bn0 + wc * 64 + ni * 32 + la;
            if (col < VOCAB) {
                const f32x16 a = (mi == 0) ? ((ni == 0) ? acc00 : acc01)
                                           : ((ni == 0) ? acc10 : acc11);
                #pragma unroll
                for (int r = 0; r < 16; ++r) {
                    const int row = rb + mi * 32 + (r & 3) + 8 * (r >> 2);
                    out[(long)row * VOCAB + col] = a[r];
                }
            }
        }
    }
}

// ---------------------------------------------------------------------------
// Kernel B (fallback): fp32 VALU GEMM — used only if workspace is too small.
// ---------------------------------------------------------------------------
#define BM 128
#define BN 128
#define KB 32
#define LDT 132

__global__ __launch_bounds__(256) void gemm_kernel(
    const float* __restrict__ ctx, const float* __restrict__ L,
    float* __restrict__ out)
{
    __shared__ float As[KB][LDT];
    __shared__ float Bs[KB][LDT];

    const int t   = threadIdx.x;
    const int bm0 = blockIdx.y * BM;
    const int bn0 = blockIdx.x * BN;
    const int tx  = t & 15, ty = t >> 4;
    const int m0  = ty * 8, nn0 = tx * 8;

    const int sr = t >> 3;
    const int sc = (t & 7) * 4;

    float acc[8][8];
    #pragma unroll
    for (int i = 0; i < 8; ++i)
        #pragma unroll
        for (int j = 0; j < 8; ++j) acc[i][j] = 0.f;

    for (int k0 = 0; k0 < DIM; k0 += KB) {
        float4 av[4], bv[4];
        #pragma unroll
        for (int i = 0; i < 4; ++i) {
            av[i] = *(const float4*)&ctx[(bm0 + sr + 32 * i) * DIM + k0 + sc];
            int v = bn0 + sr + 32 * i;
            if (v < VOCAB) bv[i] = *(const float4*)&L[(long)v * DIM + k0 + sc];
            else           bv[i] = make_float4(0.f, 0.f, 0.f, 0.f);
        }
        __syncthreads();
        #pragma unroll
        for (int i = 0; i < 4; ++i) {
            int m = sr + 32 * i;
            As[sc + 0][m] = av[i].x; As[sc + 1][m] = av[i].y;
            As[sc + 2][m] = av[i].z; As[sc + 3][m] = av[i].w;
            Bs[sc + 0][m] = bv[i].x; Bs[sc + 1][m] = bv[i].y;
            Bs[sc + 2][m] = bv[i].z; Bs[sc + 3][m] = bv[i].w;
        }
        __syncthreads();
        #pragma unroll 4
        for (int k = 0; k < KB; ++k) {
            float4 a0 = *(const float4*)&As[k][m0];
            float4 a1 = *(const float4*)&As[k][m0 + 4];
            float4 b0 = *(const float4*)&Bs[k][nn0];
            float4 b1 = *(const float4*)&Bs[k][nn0 + 4];
            float a[8] = {a0.x, a0.y, a0.z, a0.w, a1.x, a1.y, a1.z, a1.w};
            float bb[8] = {b0.x, b0.y, b0.z, b0.w, b1.x, b1.y, b1.z, b1.w};
            #pragma unroll
            for (int mi = 0; mi < 8; ++mi)
                #pragma unroll
                for (int nj = 0; nj < 8; ++nj)
                    acc[mi][nj] += a[mi] * bb[nj];
        }
    }

    if (bn0 + nn0 < VOCAB) {
        #pragma unroll
        for (int mi = 0; mi < 8; ++mi) {
            long row = bm0 + m0 + mi;
            float4 o0 = make_float4(acc[mi][0], acc[mi][1], acc[mi][2], acc[mi][3]);
            float4 o1 = make_float4(acc[mi][4], acc[mi][5], acc[mi][6], acc[mi][7]);
            *(float4*)&out[row * VOCAB + bn0 + nn0]     = o0;
            *(float4*)&out[row * VOCAB + bn0 + nn0 + 4] = o1;
        }
    }
}

// ---------------------------------------------------------------------------
// Kernel C: per-row top-32 candidates (float4 scan).
// ---------------------------------------------------------------------------
__global__ __launch_bounds__(256) void cand_kernel(
    const float* __restrict__ logits, int* __restrict__ cand)
{
    const int b = blockIdx.x, t = threadIdx.x;
    const float4* row4 = (const float4*)(logits + (long)b * VOCAB);

    float bs[8]; int bid[8];
    #pragma unroll
    for (int j = 0; j < 8; ++j) { bs[j] = -INFINITY; bid[j] = 0x7fffffff; }

    for (int i = t; i < VOCAB / 4; i += 256) {
        float4 f = row4[i];
        float sv[4] = {f.x, f.y, f.z, f.w};
        #pragma unroll
        for (int j = 0; j < 4; ++j) {
            float s = sv[j];
            if (s > bs[7]) {
                int v = i * 4 + j;
                int p = 7;
                while (p > 0 && s > bs[p - 1]) { bs[p] = bs[p - 1]; bid[p] = bid[p - 1]; --p; }
                bs[p] = s; bid[p] = v;
            }
        }
    }

    __shared__ float ls[2048];
    __shared__ int   lid[2048];
    __shared__ float rs[4];
    __shared__ int   rid[4], rpos[4];
    #pragma unroll
    for (int j = 0; j < 8; ++j) { ls[t * 8 + j] = bs[j]; lid[t * 8 + j] = bid[j]; }
    __syncthreads();

    const int lane = t & 63, wave = t >> 6;
    for (int r = 0; r < NCAND; ++r) {
        float s = -INFINITY; int id = 0x7fffffff, pos = -1;
        #pragma unroll
        for (int j = 0; j < 8; ++j) {
            int p = t * 8 + j;
            float v = ls[p]; int vi = lid[p];
            if (v > s || (v == s && vi < id)) { s = v; id = vi; pos = p; }
        }
        #pragma unroll
        for (int off = 32; off > 0; off >>= 1) {
            float os = __shfl_down(s, off);
            int   oi = __shfl_down(id, off);
            int   op = __shfl_down(pos, off);
            if (os > s || (os == s && oi < id)) { s = os; id = oi; pos = op; }
        }
        if (lane == 0) { rs[wave] = s; rid[wave] = id; rpos[wave] = pos; }
        __syncthreads();
        if (t == 0) {
            float ws = rs[0]; int wi = rid[0], wp = rpos[0];
            for (int w = 1; w < 4; ++w)
                if (rs[w] > ws || (rs[w] == ws && rid[w] < wi)) { ws = rs[w]; wi = rid[w]; wp = rpos[w]; }
            cand[b * NCAND + r] = wi;
            ls[wp] = -INFINITY;
        }
        __syncthreads();
    }
}

// ---------------------------------------------------------------------------
// Kernel D: fp64 re-rank of candidates (unchanged).
// ---------------------------------------------------------------------------
__global__ __launch_bounds__(64) void refine_kernel(
    const int* __restrict__ ids, const float* __restrict__ cet,
    const float* __restrict__ W, const float* __restrict__ bias,
    const float* __restrict__ L, const int* __restrict__ cand,
    float* __restrict__ out_ids, float* __restrict__ out_scores)
{
    const int b = blockIdx.x, l = threadIdx.x;
    __shared__ int    sids[HIST];
    __shared__ double pooled[DIM];
    if (l < HIST) sids[l] = ids[b * HIST + l];
    __syncthreads();
    #pragma unroll
    for (int d = l; d < DIM; d += 64) {
        double s = 0.0;
        for (int h = 0; h < HIST; ++h)
            s += (double)cet[(long)sids[h] * DIM + d];
        pooled[d] = s / (double)HIST;
    }
    __syncthreads();
    double c0 = (double)bias[l], c1 = (double)bias[l + 64];
    for (int k = 0; k < DIM; ++k) {
        double p = pooled[k];
        c0 += p * (double)W[k * DIM + l];
        c1 += p * (double)W[k * DIM + l + 64];
    }

    __shared__ double ss[NCAND];
    __shared__ int    sidv[NCAND];
    for (int c = 0; c < NCAND; ++c) {
        int id = cand[b * NCAND + c];
        double p = c0 * (double)L[(long)id * DIM + l]
                 + c1 * (double)L[(long)id * DIM + 64 + l];
        #pragma unroll
        for (int off = 32; off > 0; off >>= 1) p += __shfl_down(p, off);
        if (l == 0) { ss[c] = p; sidv[c] = id; }
    }
    __syncthreads();
    if (l == 0) {
        bool used[NCAND];
        for (int c = 0; c < NCAND; ++c) used[c] = false;
        for (int i = 0; i < TOPK; ++i) {
            int bi = -1; float bk = -INFINITY; int bidv = 0x7fffffff;
            for (int c = 0; c < NCAND; ++c) {
                if (used[c]) continue;
                float k32 = (float)ss[c];
                if (bi < 0 || k32 > bk || (k32 == bk && sidv[c] < bidv)) {
                    bk = k32; bi = c; bidv = sidv[c];
                }
            }
            used[bi] = true;
            out_ids[b * TOPK + i]    = (float)bidv;
            out_scores[b * TOPK + i] = bk;
        }
    }
}

// ---------------------------------------------------------------------------
extern "C" void kernel_launch(void* const* d_in, const int* in_sizes, int n_in,
                              void* d_out, int out_size, void* d_ws, size_t ws_size,
                              hipStream_t stream)
{
    const int*   ids  = (const int*)d_in[0];
    const float* cet  = (const float*)d_in[1];
    const float* let  = (const float*)d_in[2];
    const float* W    = (const float*)d_in[3];
    const float* bias = (const float*)d_in[4];

    float* out        = (float*)d_out;
    float* logits     = out;                                   // [2048,100000]
    float* out_ids    = out + (long)BATCH * VOCAB;             // [2048,10]
    float* out_scores = out_ids + BATCH * TOPK;                // [2048,10]

    // ws layout (fast path ~76 MB):
    //   ctx32 [2048,128] f32      @ 0         (1 MB)
    //   cand  [2048,32]  i32      @ 1048576   (256 KB)
    //   ch/cm/cl [2048,128] u16   @ 1310720 / 1835008 / 2359296  (512 KB each)
    //   Lh/Lm/Ll [VPAD,128] u16   @ 2883584 / 28508160 / 54132736 (24.4 MB each)
    char* ws = (char*)d_ws;
    float*  ctx32 = (float*)ws;
    int*    cand  = (int*)(ws + 1048576);
    ushort* ch    = (ushort*)(ws + 1310720);
    ushort* cm    = (ushort*)(ws + 1835008);
    ushort* cl    = (ushort*)(ws + 2359296);
    ushort* Lh    = (ushort*)(ws + 2883584);
    ushort* Lm    = (ushort*)(ws + 28508160);
    ushort* Ll    = (ushort*)(ws + 54132736);
    const size_t WS_NEED = 79757312ull;

    const bool fast = (ws_size >= WS_NEED);

    if (fast) {
        conv_kernel<<<VPAD * 32 / 256, 256, 0, stream>>>(let, Lh, Lm, Ll);
        ctx_kernel<<<BATCH, 128, 0, stream>>>(ids, cet, W, bias, ctx32, ch, cm, cl);
        mfma_gemm<<<NWG, 256, 0, stream>>>(ch, cm, cl, Lh, Lm, Ll, logits);
    } else {
        ctx_kernel<<<BATCH, 128, 0, stream>>>(ids, cet, W, bias, ctx32,
                                              nullptr, nullptr, nullptr);
        dim3 grid((VOCAB + BN - 1) / BN, BATCH / BM);
        gemm_kernel<<<grid, 256, 0, stream>>>(ctx32, let, logits);
    }

    cand_kernel<<<BATCH, 256, 0, stream>>>(logits, cand);

    refine_kernel<<<BATCH, 64, 0, stream>>>(ids, cet, W, bias, let, cand,
                                            out_ids, out_scores);
}